// Round 14
// baseline (128.871 us; speedup 1.0000x reference)
//
#include <hip/hip_runtime.h>
#include <hip/hip_bf16.h>

#define DDIM 256
#define NROWS 8192

typedef __attribute__((ext_vector_type(4))) int int4v;
typedef __attribute__((ext_vector_type(8))) int int8v;
typedef __attribute__((ext_vector_type(16))) float f32x16;

// async global->LDS, 16B per lane. LDS dest is wave-uniform base + lane*16.
__device__ __forceinline__ void async16(const void* g, void* l) {
    __builtin_amdgcn_global_load_lds(
        (const __attribute__((address_space(1))) unsigned int*)g,
        (__attribute__((address_space(3))) unsigned int*)l,
        16, 0, 0);
}

// raw v_exp_f32: returns 2^x (one transcendental)
__device__ __forceinline__ float fexp2(float x) {
    float r; asm("v_exp_f32 %0, %1" : "=v"(r) : "v"(x)); return r;
}

// Kernel 1 (REWRITTEN): L2-normalize rows of U and P to FP8 e4m3, compute
// pos_sim fp32-exact, zero rowsum/out/counter.
// Old: 1 wave/row, 32 B/thread, 18 serial 64-wide shuffle stages -> latency-
// chain-bound (est. 25-55 us, the largest unmeasured chunk of total-sim).
// New: 16 lanes/row (512 blocks x 256 thr), 128 B/thread (8 float4 loads in
// flight), 4 shuffle stages at width 16, one coalesced 16-B fp8 store per
// matrix per lane. Traffic 20 MB -> ~10 us target.
__global__ __launch_bounds__(256) void normalize_kernel(
    const float* __restrict__ U, const float* __restrict__ P,
    unsigned char* __restrict__ Un, unsigned char* __restrict__ Pn,
    float* __restrict__ possim, float* __restrict__ rowsum,
    float* __restrict__ out, int* __restrict__ counter)
{
    if (blockIdx.x == 0 && threadIdx.x == 0) { out[0] = 0.0f; counter[0] = 0; }
    const int tid = threadIdx.x;
    const int row = blockIdx.x * 16 + (tid >> 4);   // 512 x 16 = 8192 rows
    const int sl  = tid & 15;                       // sub-lane within row
    const float* Ur = U + (size_t)row * DDIM + sl * 16;
    const float* Pr = P + (size_t)row * DDIM + sl * 16;

    float4 u[4], p[4];
    #pragma unroll
    for (int j = 0; j < 4; ++j) {
        u[j] = *(const float4*)(Ur + j * 4);
        p[j] = *(const float4*)(Pr + j * 4);
    }
    float su = 0.0f, sp = 0.0f, up = 0.0f;
    #pragma unroll
    for (int j = 0; j < 4; ++j) {
        su += u[j].x*u[j].x + u[j].y*u[j].y + u[j].z*u[j].z + u[j].w*u[j].w;
        sp += p[j].x*p[j].x + p[j].y*p[j].y + p[j].z*p[j].z + p[j].w*p[j].w;
        up += u[j].x*p[j].x + u[j].y*p[j].y + u[j].z*p[j].z + u[j].w*p[j].w;
    }
    #pragma unroll
    for (int d = 1; d < 16; d <<= 1) {
        su += __shfl_xor(su, d, 16);
        sp += __shfl_xor(sp, d, 16);
        up += __shfl_xor(up, d, 16);
    }
    const float iu = rsqrtf(fmaxf(su, 1e-24f));
    const float ip = rsqrtf(fmaxf(sp, 1e-24f));
    if (sl == 0) {
        possim[row] = up * iu * ip;
        rowsum[row] = 0.0f;
    }
    int4v wu, wp;
    #pragma unroll
    for (int j = 0; j < 4; ++j) {
        unsigned w = (unsigned)__builtin_amdgcn_cvt_pk_fp8_f32(
            u[j].x * iu, u[j].y * iu, 0, false);
        w = (unsigned)__builtin_amdgcn_cvt_pk_fp8_f32(
            u[j].z * iu, u[j].w * iu, (int)w, true);
        wu[j] = (int)w;
        unsigned v = (unsigned)__builtin_amdgcn_cvt_pk_fp8_f32(
            p[j].x * ip, p[j].y * ip, 0, false);
        v = (unsigned)__builtin_amdgcn_cvt_pk_fp8_f32(
            p[j].z * ip, p[j].w * ip, (int)v, true);
        wp[j] = (int)v;
    }
    *(int4v*)(Un + (size_t)row * DDIM + sl * 16) = wu;
    *(int4v*)(Pn + (size_t)row * DDIM + sl * 16) = wp;
}

// Kernel 2: persistent-A FP8 GEMM (mfma_scale_f32_32x32x64_f8f6f4, unit
// E8M0 scales = plain fp8 at 2x bf16 rate) + exp-rowsum + fused finalize.
// R11 VERBATIM (best measured: sim 67.2 us, absmax 0.0): 256 blocks x 512
// thr (8 waves, 1/CU), block = 256 rows x 1024 cols, wave = 32 rows, 16
// col-slots of 64, quad-buffered B (4 x 16 KB = 64 KB LDS), counted-vmcnt
// ladder 4/2/0, stage-after-barrier. R12 (2 blk/CU) = 92 us and R13
// (8 x 128-col slots) = 69.4 us both refuted their hypotheses; R11 stands.
// Fragment layouts (32x32x64 f8f6f4):
//   A: row = lane&31, k = (lane>>5)*32 + i ;  B symmetric (col = lane&31)
//   C/D: col = lane&31, row = (g&3) + 8*(g>>2) + 4*(lane>>5)
// LDS tile 64 rows x 256 B; granule-16 XOR swizzle g^(row&15), involution
// on async16 SOURCE and ds_read addr (rule #21).
__global__ __launch_bounds__(512, 2) void sim_exp_rowsum(
    const unsigned char* __restrict__ Un,
    const unsigned char* __restrict__ Pn,
    float* __restrict__ rowsum,
    const float* __restrict__ possim,
    int* __restrict__ counter,
    float* __restrict__ out)
{
    __shared__ __align__(16) unsigned char lds[65536];   // 4 x 16 KB fp8 B bufs
    __shared__ float ws8[8];
    __shared__ int ticket_s;

    const int tid  = threadIdx.x;
    const int lane = tid & 63;
    const int wv   = tid >> 6;          // 0..7, each wave owns 32 A-rows
    const int m32  = lane & 31;
    const int hi   = lane >> 5;

    const int stripe = blockIdx.x >> 3;   // 0..31  (256-row stripes)
    const int oct    = blockIdx.x & 7;    // 0..7   (1024-col groups == XCD)

    // ---- A-frags straight from global fp8 (one-time, L2/L3-hot) ----
    const unsigned char* Arow = Un
        + (size_t)(stripe * 256 + wv * 32 + m32) * DDIM + hi * 32;
    union A8 { int8v v; int4v h[2]; };
    A8 afr[4];
    #pragma unroll
    for (int kc = 0; kc < 4; ++kc) {
        afr[kc].h[0] = *(const int4v*)(Arow + kc * 64);
        afr[kc].h[1] = *(const int4v*)(Arow + kc * 64 + 16);
    }

    // ---- B LDS addressing (swizzle pre-folded) ----
    // addr = m32*256 + ((hi*2+h)^xlo)*16 + (kc*64 ^ xh16) + n*8192
    const int x = m32 & 15, xlo = x & 3;
    const unsigned xh16 = (unsigned)((x & 12) * 16);
    const unsigned bA = (unsigned)(m32 * 256 + (((hi * 2 + 0) ^ xlo) * 16));
    const unsigned bB = (unsigned)(m32 * 256 + (((hi * 2 + 1) ^ xlo) * 16));
    unsigned kterm[4];
    #pragma unroll
    for (int kc = 0; kc < 4; ++kc)
        kterm[kc] = (unsigned)(kc * 64) ^ xh16;

    // ---- staging offsets: wave stages 8 rows (2 KB) per tile, 2 async16 ----
    unsigned soff0, soff1;
    {
        const int r0 = wv * 8 + 0 * 4 + (lane >> 4);
        const int r1 = wv * 8 + 1 * 4 + (lane >> 4);
        const int gp = lane & 15;
        soff0 = (unsigned)(r0 * 256 + ((gp ^ (r0 & 15)) * 16));
        soff1 = (unsigned)(r1 * 256 + ((gp ^ (r1 & 15)) * 16));
    }

    const unsigned char* Bglob = Pn + (size_t)(oct * 1024) * DDIM;

#define STG(T, BUF)                                                          \
    do {                                                                     \
        async16(Bglob + (size_t)(T) * 16384 + soff0,                         \
                lds + (BUF) * 16384 + wv * 2048);                            \
        async16(Bglob + (size_t)(T) * 16384 + soff1,                         \
                lds + (BUF) * 16384 + wv * 2048 + 1024);                     \
    } while (0)

    float rowpart[16];
    #pragma unroll
    for (int g = 0; g < 16; ++g) rowpart[g] = 0.0f;

    // ---- Prologue: stage tiles 0..2, full drain (also covers A-loads) ----
    STG(0, 0); STG(1, 1); STG(2, 2);
    asm volatile("s_waitcnt vmcnt(0)" ::: "memory");
    __builtin_amdgcn_s_barrier();

    // ---- Main loop: 16 col-slots of 64 fp8 cols ----
    for (int i = 0; i < 16; ++i) {
        if (i > 0) {
            // tile i done; tiles i+1, i+2 (2 loads each) stay in flight
            if (i <= 13)      asm volatile("s_waitcnt vmcnt(4)" ::: "memory");
            else if (i == 14) asm volatile("s_waitcnt vmcnt(2)" ::: "memory");
            else              asm volatile("s_waitcnt vmcnt(0)" ::: "memory");
            __builtin_amdgcn_s_barrier();   // frees buf (i+3)&3
        }
        if (i + 3 < 16) STG(i + 3, (i + 3) & 3);

        const unsigned char* Bp = lds + (i & 3) * 16384;
        f32x16 acc0, acc1;
        #pragma unroll
        for (int g = 0; g < 16; ++g) { acc0[g] = 0.0f; acc1[g] = 0.0f; }

        #pragma unroll
        for (int kc = 0; kc < 4; ++kc) {
            A8 b0, b1;
            b0.h[0] = *(const int4v*)(Bp + bA + kterm[kc]);
            b0.h[1] = *(const int4v*)(Bp + bB + kterm[kc]);
            b1.h[0] = *(const int4v*)(Bp + bA + kterm[kc] + 8192);
            b1.h[1] = *(const int4v*)(Bp + bB + kterm[kc] + 8192);
            __builtin_amdgcn_s_setprio(1);
            acc0 = __builtin_amdgcn_mfma_scale_f32_32x32x64_f8f6f4(
                afr[kc].v, b0.v, acc0, 0, 0,
                0, 0x7F7F7F7F, 0, 0x7F7F7F7F);   // fp8/fp8, unit scales
            acc1 = __builtin_amdgcn_mfma_scale_f32_32x32x64_f8f6f4(
                afr[kc].v, b1.v, acc1, 0, 0,
                0, 0x7F7F7F7F, 0, 0x7F7F7F7F);
            __builtin_amdgcn_s_setprio(0);
        }

        // exp(5*sim) = 2^(sim*5*log2 e)
        #pragma unroll
        for (int g = 0; g < 16; ++g)
            rowpart[g] += fexp2(acc0[g] * 7.2134752044448169f)
                        + fexp2(acc1[g] * 7.2134752044448169f);
    }
#undef STG

    // ---- Epilogue: reduce 32 column-lanes, one atomic per row-slot ----
    // C/D: col = lane&31, row = (g&3) + 8*(g>>2) + 4*hi.
    #pragma unroll
    for (int g = 0; g < 16; ++g) {
        float s = rowpart[g];
        s += __shfl_xor(s, 1);
        s += __shfl_xor(s, 2);
        s += __shfl_xor(s, 4);
        s += __shfl_xor(s, 8);
        s += __shfl_xor(s, 16);
        if (m32 == 0) {
            const int grow = stripe * 256 + wv * 32
                           + (g & 3) + 8 * (g >> 2) + 4 * hi;
            atomicAdd(&rowsum[grow], s);
        }
    }

    // ---- Fused finalize: last block computes the loss ----
    __threadfence();
    __syncthreads();   // this block's atomics are visible
    if (tid == 0)
        ticket_s = __hip_atomic_fetch_add(counter, 1, __ATOMIC_ACQ_REL,
                                          __HIP_MEMORY_SCOPE_AGENT);
    __syncthreads();
    if (ticket_s == 255) {
        float part = 0.0f;
        for (int i = tid; i < NROWS; i += 512) {
            const float rs = __hip_atomic_load(&rowsum[i], __ATOMIC_RELAXED,
                                               __HIP_MEMORY_SCOPE_AGENT);
            part += __logf(rs) - 5.0f * possim[i];
        }
        #pragma unroll
        for (int d = 1; d < 64; d <<= 1) part += __shfl_xor(part, d);
        if ((tid & 63) == 0) ws8[wv] = part;
        __syncthreads();
        if (tid == 0) {
            float tot = 0.0f;
            #pragma unroll
            for (int w = 0; w < 8; ++w) tot += ws8[w];
            out[0] = tot * (1.0f / (float)NROWS);
        }
    }
}

extern "C" void kernel_launch(void* const* d_in, const int* in_sizes, int n_in,
                              void* d_out, int out_size, void* d_ws, size_t ws_size,
                              hipStream_t stream) {
    const float* U = (const float*)d_in[0];
    const float* P = (const float*)d_in[1];
    float* out = (float*)d_out;
    char* ws = (char*)d_ws;
    // ws: Un fp8 (2 MB) | Pn fp8 (2 MB) | ... | rowsum f32 @8 MB | possim | counter
    unsigned char* Un = (unsigned char*)ws;
    unsigned char* Pn = (unsigned char*)(ws + 2097152);
    float* rowsum = (float*)(ws + 8388608);
    float* possim = (float*)(ws + 8388608 + 32768);
    int* counter  = (int*)(ws + 8388608 + 65536);

    normalize_kernel<<<NROWS / 16, 256, 0, stream>>>(U, P, Un, Pn, possim, rowsum,
                                                     out, counter);
    sim_exp_rowsum<<<256, 512, 0, stream>>>(Un, Pn, rowsum, possim, counter, out);
}